// Round 1
// baseline (5391.214 us; speedup 1.0000x reference)
//
#include <hip/hip_runtime.h>
#include <stdint.h>

// JAX PRNG mode: 1 = threefry_partitionable (JAX >= 0.4.36 default), 0 = legacy/original.
#ifndef JAX_PARTITIONABLE
#define JAX_PARTITIONABLE 1
#endif

#define DIM    512
#define NTOT   32768
#define NMAJ   24576
#define NMIN   8192
#define NGEN   16384                       // NMIN * 2
#define XROWS  49152                       // NTOT + NGEN
#define Y_OFF  ((size_t)XROWS * DIM)       // 25165824

// ---------------- threefry2x32 (Random123 / JAX schedule) ----------------
__device__ __forceinline__ void tf2x32(uint32_t k0, uint32_t k1,
                                       uint32_t x0, uint32_t x1,
                                       uint32_t &o0, uint32_t &o1) {
  const uint32_t ks2 = k0 ^ k1 ^ 0x1BD11BDAu;
  x0 += k0; x1 += k1;
#define TF_R(r) { x0 += x1; x1 = (x1 << (r)) | (x1 >> (32 - (r))); x1 ^= x0; }
  TF_R(13) TF_R(15) TF_R(26) TF_R(6)
  x0 += k1;  x1 += ks2 + 1u;
  TF_R(17) TF_R(29) TF_R(16) TF_R(24)
  x0 += ks2; x1 += k0 + 2u;
  TF_R(13) TF_R(15) TF_R(26) TF_R(6)
  x0 += k0;  x1 += k1 + 3u;
  TF_R(17) TF_R(29) TF_R(16) TF_R(24)
  x0 += k1;  x1 += ks2 + 4u;
  TF_R(13) TF_R(15) TF_R(26) TF_R(6)
  x0 += ks2; x1 += k0 + 5u;
#undef TF_R
  o0 = x0; o1 = x1;
}

#if JAX_PARTITIONABLE
__device__ __forceinline__ void jax_split(uint2 key, uint2 &c0, uint2 &c1) {
  tf2x32(key.x, key.y, 0u, 0u, c0.x, c0.y);
  tf2x32(key.x, key.y, 0u, 1u, c1.x, c1.y);
}
__device__ __forceinline__ uint32_t jax_bits(uint2 key, uint32_t f) {
  uint32_t a, b;
  tf2x32(key.x, key.y, 0u, f, a, b);
  return a ^ b;
}
#else
__device__ __forceinline__ void jax_split(uint2 key, uint2 &c0, uint2 &c1) {
  uint32_t a0, b0, a1, b1;
  tf2x32(key.x, key.y, 0u, 2u, a0, b0);
  tf2x32(key.x, key.y, 1u, 3u, a1, b1);
  c0 = make_uint2(a0, a1);
  c1 = make_uint2(b0, b1);
}
__device__ __forceinline__ uint32_t jax_bits(uint2 key, uint32_t f) {
  uint32_t a, b;
  if (f < (NGEN / 2)) { tf2x32(key.x, key.y, f, f + NGEN / 2, a, b); return a; }
  tf2x32(key.x, key.y, f - NGEN / 2, f, a, b); return b;
}
#endif

// key(42) -> split -> (.., sub); split(sub) -> (k1, k2); split(k1) -> (.., k2i)
// choice bits use k2i (randint lower bits); u bits use k2.
__device__ __forceinline__ void derive_keys(uint2 &k2, uint2 &k2i) {
  uint2 root = make_uint2(0u, 42u);
  uint2 dead, sub, k1;
  jax_split(root, dead, sub);
  jax_split(sub, k1, k2);
  jax_split(k1, dead, k2i);
}

// ---------------- kernel 0: minority row squared norms (fp64 -> fp32) ----
__global__ __launch_bounds__(256) void sq_kernel(const float* __restrict__ X,
                                                 float* __restrict__ out) {
  const int row  = blockIdx.x * 4 + (threadIdx.x >> 6);
  const int lane = threadIdx.x & 63;
  const float* Xm = X + (size_t)NMAJ * DIM;
  const float4* p = reinterpret_cast<const float4*>(Xm + (size_t)row * DIM);
  double s = 0.0;
#pragma unroll
  for (int q = 0; q < 2; ++q) {
    float4 v = p[lane + q * 64];
    s += (double)v.x * v.x + (double)v.y * v.y + (double)v.z * v.z + (double)v.w * v.w;
  }
#pragma unroll
  for (int off = 32; off > 0; off >>= 1) s += __shfl_down(s, off);
  if (lane == 0) out[Y_OFF + row] = (float)s;   // scratch in y-region, overwritten later
}

// ---------------- kernel 1: distances + top-5 + generate ----------------
__global__ __launch_bounds__(256) void smote_main(const float* __restrict__ X,
                                                  float* __restrict__ out) {
  __shared__ __align__(16) float At[64][32];   // [k][row]
  __shared__ __align__(16) float Bt[64][64];   // [k][col]
  __shared__ float Dt[32][65];                 // padded stride vs bank conflicts
  __shared__ int   nbr_s[32][4];
  __shared__ float u_s[64];
  __shared__ int   nb_s[64];

  const float* Xm = X + (size_t)NMAJ * DIM;
  const float* sq = out + Y_OFF;               // written by sq_kernel
  const int r0  = blockIdx.x * 32;
  const int tid = threadIdx.x;
  const int tr  = tid >> 4;                    // 0..15 -> rows tr*2, tr*2+1
  const int tc  = tid & 15;                    // 0..15 -> cols tc*4 .. +3

  float td0 = 1e30f, td1 = 1e30f, td2 = 1e30f, td3 = 1e30f, td4 = 1e30f;
  int   ti0 = 0,     ti1 = 0,     ti2 = 0,     ti3 = 0,     ti4 = 0;

  for (int ct = 0; ct < NMIN / 64; ++ct) {
    const int c0 = ct * 64;
    double a00 = 0, a01 = 0, a02 = 0, a03 = 0;
    double a10 = 0, a11 = 0, a12 = 0, a13 = 0;

    for (int kt = 0; kt < DIM / 64; ++kt) {
      const int k0 = kt * 64;
      __syncthreads();
      // stage A tile (32x64) transposed: 2 float4 per thread
      {
        int f = tid, r = f >> 4, c4 = f & 15;
        float4 v = *reinterpret_cast<const float4*>(Xm + (size_t)(r0 + r) * DIM + k0 + c4 * 4);
        At[c4*4+0][r] = v.x; At[c4*4+1][r] = v.y; At[c4*4+2][r] = v.z; At[c4*4+3][r] = v.w;
        f = tid + 256; r = f >> 4; c4 = f & 15;
        v = *reinterpret_cast<const float4*>(Xm + (size_t)(r0 + r) * DIM + k0 + c4 * 4);
        At[c4*4+0][r] = v.x; At[c4*4+1][r] = v.y; At[c4*4+2][r] = v.z; At[c4*4+3][r] = v.w;
      }
      // stage B tile (64x64) transposed: 4 float4 per thread
#pragma unroll
      for (int q = 0; q < 4; ++q) {
        int f = tid + q * 256, r = f >> 4, c4 = f & 15;
        float4 v = *reinterpret_cast<const float4*>(Xm + (size_t)(c0 + r) * DIM + k0 + c4 * 4);
        Bt[c4*4+0][r] = v.x; Bt[c4*4+1][r] = v.y; Bt[c4*4+2][r] = v.z; Bt[c4*4+3][r] = v.w;
      }
      __syncthreads();
#pragma unroll 8
      for (int kk = 0; kk < 64; ++kk) {
        float aa0 = At[kk][tr * 2], aa1 = At[kk][tr * 2 + 1];
        float4 b = *reinterpret_cast<const float4*>(&Bt[kk][tc * 4]);
        a00 += (double)aa0 * b.x; a01 += (double)aa0 * b.y;
        a02 += (double)aa0 * b.z; a03 += (double)aa0 * b.w;
        a10 += (double)aa1 * b.x; a11 += (double)aa1 * b.y;
        a12 += (double)aa1 * b.z; a13 += (double)aa1 * b.w;
      }
    }
    // emulate reference fp32 chain: d2 = (sq_i + sq_j) - 2*dot ; D = sqrt(max(d2,0))
    {
      const float si0 = sq[r0 + tr * 2], si1 = sq[r0 + tr * 2 + 1];
      const float sj0 = sq[c0 + tc * 4 + 0], sj1 = sq[c0 + tc * 4 + 1];
      const float sj2 = sq[c0 + tc * 4 + 2], sj3 = sq[c0 + tc * 4 + 3];
      Dt[tr*2+0][tc*4+0] = (float)sqrt((double)fmaxf((si0 + sj0) - 2.0f * (float)a00, 0.0f));
      Dt[tr*2+0][tc*4+1] = (float)sqrt((double)fmaxf((si0 + sj1) - 2.0f * (float)a01, 0.0f));
      Dt[tr*2+0][tc*4+2] = (float)sqrt((double)fmaxf((si0 + sj2) - 2.0f * (float)a02, 0.0f));
      Dt[tr*2+0][tc*4+3] = (float)sqrt((double)fmaxf((si0 + sj3) - 2.0f * (float)a03, 0.0f));
      Dt[tr*2+1][tc*4+0] = (float)sqrt((double)fmaxf((si1 + sj0) - 2.0f * (float)a10, 0.0f));
      Dt[tr*2+1][tc*4+1] = (float)sqrt((double)fmaxf((si1 + sj1) - 2.0f * (float)a11, 0.0f));
      Dt[tr*2+1][tc*4+2] = (float)sqrt((double)fmaxf((si1 + sj2) - 2.0f * (float)a12, 0.0f));
      Dt[tr*2+1][tc*4+3] = (float)sqrt((double)fmaxf((si1 + sj3) - 2.0f * (float)a13, 0.0f));
    }
    __syncthreads();
    // per-row stable top-5 (strict < + increasing j == stable argsort order)
    if (tid < 32) {
      for (int j = 0; j < 64; ++j) {
        float d = Dt[tid][j];
        if (d < td4) {
          int jj = c0 + j;
          if (d < td3) { td4 = td3; ti4 = ti3;
            if (d < td2) { td3 = td2; ti3 = ti2;
              if (d < td1) { td2 = td1; ti2 = ti1;
                if (d < td0) { td1 = td0; ti1 = ti0; td0 = d; ti0 = jj; }
                else { td1 = d; ti1 = jj; }
              } else { td2 = d; ti2 = jj; }
            } else { td3 = d; ti3 = jj; }
          } else { td4 = d; ti4 = jj; }
        }
      }
    }
    // Dt reuse protected by the kt-loop leading __syncthreads of next ct
  }

  if (tid < 32) {   // argsort cols 1..4 (col 0 is self, D == 0)
    nbr_s[tid][0] = ti1; nbr_s[tid][1] = ti2; nbr_s[tid][2] = ti3; nbr_s[tid][3] = ti4;
  }
  __syncthreads();

  if (tid < 64) {
    uint2 k2, k2i;
    derive_keys(k2, k2i);
    const uint32_t f = (uint32_t)(2 * r0 + tid);      // flat index into (8192,2)
    const uint32_t ch = jax_bits(k2i, f) & 3u;        // randint(0,4): lower_bits % 4
    nb_s[tid] = nbr_s[tid >> 1][ch];
    const uint32_t ub = jax_bits(k2, f);
    u_s[tid] = __uint_as_float((ub >> 9) | 0x3f800000u) - 1.0f;
  }
  __syncthreads();

  // write 64 generated rows: out_row = base + u * (nbr - base)
  const int c = tid * 2;
  for (int g = 0; g < 64; ++g) {
    const int i = g >> 1;
    const float u = u_s[g];
    const int nb = nb_s[g];
    float2 bv = *reinterpret_cast<const float2*>(Xm + (size_t)(r0 + i) * DIM + c);
    float2 nv = *reinterpret_cast<const float2*>(Xm + (size_t)nb * DIM + c);
    float2 o;
    o.x = bv.x + u * (nv.x - bv.x);
    o.y = bv.y + u * (nv.y - bv.y);
    *reinterpret_cast<float2*>(out + ((size_t)(NTOT + 2 * r0 + g)) * DIM + c) = o;
  }
}

// ---------------- kernel 2: passthrough X + y_out (overwrites sq scratch) --
__global__ __launch_bounds__(256) void copy_kernel(const float* __restrict__ X,
                                                   const int* __restrict__ y,
                                                   float* __restrict__ out) {
  const long long XF4 = (long long)NTOT * DIM / 4;   // 4194304
  const long long YF4 = XROWS / 4;                   // 12288
  long long idx = (long long)blockIdx.x * blockDim.x + threadIdx.x;
  const long long stride = (long long)gridDim.x * blockDim.x;
  for (long long i = idx; i < XF4 + YF4; i += stride) {
    if (i < XF4) {
      reinterpret_cast<float4*>(out)[i] = reinterpret_cast<const float4*>(X)[i];
    } else {
      long long j = i - XF4;
      float4 o;
      if (j < NTOT / 4) {
        int4 yv = reinterpret_cast<const int4*>(y)[j];
        o.x = (float)yv.x; o.y = (float)yv.y; o.z = (float)yv.z; o.w = (float)yv.w;
      } else {
        o.x = o.y = o.z = o.w = 1.0f;
      }
      reinterpret_cast<float4*>(out + Y_OFF)[j] = o;
    }
  }
}

extern "C" void kernel_launch(void* const* d_in, const int* in_sizes, int n_in,
                              void* d_out, int out_size, void* d_ws, size_t ws_size,
                              hipStream_t stream) {
  const float* X = (const float*)d_in[0];
  const int*   y = (const int*)d_in[1];
  float* out = (float*)d_out;
  (void)in_sizes; (void)n_in; (void)out_size; (void)d_ws; (void)ws_size;

  sq_kernel  <<<dim3(NMIN / 4), dim3(256), 0, stream>>>(X, out);
  smote_main <<<dim3(NMIN / 32), dim3(256), 0, stream>>>(X, out);
  copy_kernel<<<dim3(2048),      dim3(256), 0, stream>>>(X, y, out);
}

// Round 2
// 2058.518 us; speedup vs baseline: 2.6190x; 2.6190x over previous
//
#include <hip/hip_runtime.h>
#include <stdint.h>
#include <math.h>

// JAX PRNG mode: 1 = threefry_partitionable (JAX >= 0.4.36 default), 0 = legacy/original.
#ifndef JAX_PARTITIONABLE
#define JAX_PARTITIONABLE 1
#endif

#define DIM    512
#define NTOT   32768
#define NMAJ   24576
#define NMIN   8192
#define NGEN   16384                       // NMIN * 2
#define XROWS  49152                       // NTOT + NGEN
#define Y_OFF  ((size_t)XROWS * DIM)       // 25165824

// ws float-index layout: [0,8192) sq ; [8192, 8192+163840) partial d ; then partial i
#define WS_PD  (NMIN)
#define WS_PI  (NMIN + NMIN * 20)

// ---------------- threefry2x32 (Random123 / JAX schedule) ----------------
__device__ __forceinline__ void tf2x32(uint32_t k0, uint32_t k1,
                                       uint32_t x0, uint32_t x1,
                                       uint32_t &o0, uint32_t &o1) {
  const uint32_t ks2 = k0 ^ k1 ^ 0x1BD11BDAu;
  x0 += k0; x1 += k1;
#define TF_R(r) { x0 += x1; x1 = (x1 << (r)) | (x1 >> (32 - (r))); x1 ^= x0; }
  TF_R(13) TF_R(15) TF_R(26) TF_R(6)
  x0 += k1;  x1 += ks2 + 1u;
  TF_R(17) TF_R(29) TF_R(16) TF_R(24)
  x0 += ks2; x1 += k0 + 2u;
  TF_R(13) TF_R(15) TF_R(26) TF_R(6)
  x0 += k0;  x1 += k1 + 3u;
  TF_R(17) TF_R(29) TF_R(16) TF_R(24)
  x0 += k1;  x1 += ks2 + 4u;
  TF_R(13) TF_R(15) TF_R(26) TF_R(6)
  x0 += ks2; x1 += k0 + 5u;
#undef TF_R
  o0 = x0; o1 = x1;
}

#if JAX_PARTITIONABLE
__device__ __forceinline__ void jax_split(uint2 key, uint2 &c0, uint2 &c1) {
  tf2x32(key.x, key.y, 0u, 0u, c0.x, c0.y);
  tf2x32(key.x, key.y, 0u, 1u, c1.x, c1.y);
}
__device__ __forceinline__ uint32_t jax_bits(uint2 key, uint32_t f) {
  uint32_t a, b;
  tf2x32(key.x, key.y, 0u, f, a, b);
  return a ^ b;
}
#else
__device__ __forceinline__ void jax_split(uint2 key, uint2 &c0, uint2 &c1) {
  uint32_t a0, b0, a1, b1;
  tf2x32(key.x, key.y, 0u, 2u, a0, b0);
  tf2x32(key.x, key.y, 1u, 3u, a1, b1);
  c0 = make_uint2(a0, a1);
  c1 = make_uint2(b0, b1);
}
__device__ __forceinline__ uint32_t jax_bits(uint2 key, uint32_t f) {
  uint32_t a, b;
  if (f < (NGEN / 2)) { tf2x32(key.x, key.y, f, f + NGEN / 2, a, b); return a; }
  tf2x32(key.x, key.y, f - NGEN / 2, f, a, b); return b;
}
#endif

__device__ __forceinline__ void derive_keys(uint2 &k2, uint2 &k2i) {
  uint2 root = make_uint2(0u, 42u);
  uint2 dead, sub, k1;
  jax_split(root, dead, sub);
  jax_split(sub, k1, k2);
  jax_split(k1, dead, k2i);
}

// ---------------- kernel 0: minority row squared norms (fp64 -> fp32) ----
__global__ __launch_bounds__(256) void sq_kernel(const float* __restrict__ X,
                                                 float* __restrict__ wsf) {
  const int row  = blockIdx.x * 4 + (threadIdx.x >> 6);
  const int lane = threadIdx.x & 63;
  const float* Xm = X + (size_t)NMAJ * DIM;
  const float4* p = reinterpret_cast<const float4*>(Xm + (size_t)row * DIM);
  double s = 0.0;
#pragma unroll
  for (int q = 0; q < 2; ++q) {
    float4 v = p[lane + q * 64];
    s += (double)v.x * v.x + (double)v.y * v.y + (double)v.z * v.z + (double)v.w * v.w;
  }
#pragma unroll
  for (int off = 32; off > 0; off >>= 1) s += __shfl_down(s, off);
  if (lane == 0) wsf[row] = (float)s;
}

// strict-< 5-deep insertion (ascending j within a thread => stable order)
#define INSERT5(TD, TI, dv, jv)                                          \
  if ((dv) < TD[4]) {                                                    \
    if ((dv) < TD[3]) { TD[4]=TD[3]; TI[4]=TI[3];                        \
      if ((dv) < TD[2]) { TD[3]=TD[2]; TI[3]=TI[2];                      \
        if ((dv) < TD[1]) { TD[2]=TD[1]; TI[2]=TI[1];                    \
          if ((dv) < TD[0]) { TD[1]=TD[0]; TI[1]=TI[0]; TD[0]=(dv); TI[0]=(jv); } \
          else { TD[1]=(dv); TI[1]=(jv); } }                             \
        else { TD[2]=(dv); TI[2]=(jv); } }                               \
      else { TD[3]=(dv); TI[3]=(jv); } }                                 \
    else { TD[4]=(dv); TI[4]=(jv); } }

// ---------------- kernel 1: 64x128-tile fp64 syrk + per-quarter top-5 ----
// grid = 512 blocks: rowg = bid>>2 (64 rows), colq = bid&3 (2048 cols)
__global__ __launch_bounds__(256, 2) void smote_main(const float* __restrict__ X,
                                                     float* __restrict__ wsf) {
  __shared__ __align__(16) char raw[40960];
  float* At = reinterpret_cast<float*>(raw);        // [32][64]  k-major
  float* Bt = At + 32 * 64;                         // [32][128] k-major

  const float* Xm = X + (size_t)NMAJ * DIM;
  const float* sq = wsf;
  const int rowg = blockIdx.x >> 2;
  const int colq = blockIdx.x & 3;
  const int r0 = rowg * 64;
  const int cb = colq * 2048;
  const int tid = threadIdx.x;
  const int ty = tid >> 4;      // 0..15 -> rows ty*4..+3
  const int tx = tid & 15;      // 0..15 -> cols tx*8..+7

  float td[4][5];
  int   ti[4][5];
#pragma unroll
  for (int i = 0; i < 4; ++i)
#pragma unroll
    for (int s = 0; s < 5; ++s) { td[i][s] = 1e30f; ti[i][s] = 0x7fffffff; }

  float si[4];
#pragma unroll
  for (int i = 0; i < 4; ++i) si[i] = sq[r0 + ty * 4 + i];

  for (int ct = 0; ct < 16; ++ct) {
    const int c0 = cb + ct * 128;
    double acc[4][8];
#pragma unroll
    for (int i = 0; i < 4; ++i)
#pragma unroll
      for (int j = 0; j < 8; ++j) acc[i][j] = 0.0;

    for (int kt = 0; kt < 16; ++kt) {
      const int k0 = kt * 32;
      __syncthreads();
      // stage A (64 rows x 32 k, k-major). lane-fast = LDS row -> 2-way banks (free)
#pragma unroll
      for (int q = 0; q < 2; ++q) {
        const int r  = tid & 63;
        const int c4 = (tid >> 6) + 4 * q;
        float4 v = *reinterpret_cast<const float4*>(Xm + (size_t)(r0 + r) * DIM + k0 + c4 * 4);
        At[(4 * c4 + 0) * 64 + r] = v.x;
        At[(4 * c4 + 1) * 64 + r] = v.y;
        At[(4 * c4 + 2) * 64 + r] = v.z;
        At[(4 * c4 + 3) * 64 + r] = v.w;
      }
      // stage B (128 cols x 32 k, k-major)
#pragma unroll
      for (int q = 0; q < 4; ++q) {
        const int col = (tid & 63) + 64 * (q & 1);
        const int c4  = (tid >> 6) + 4 * (q >> 1);
        float4 v = *reinterpret_cast<const float4*>(Xm + (size_t)(c0 + col) * DIM + k0 + c4 * 4);
        Bt[(4 * c4 + 0) * 128 + col] = v.x;
        Bt[(4 * c4 + 1) * 128 + col] = v.y;
        Bt[(4 * c4 + 2) * 128 + col] = v.z;
        Bt[(4 * c4 + 3) * 128 + col] = v.w;
      }
      __syncthreads();
#pragma unroll 8
      for (int kk = 0; kk < 32; ++kk) {
        const float4 a  = *reinterpret_cast<const float4*>(&At[kk * 64 + ty * 4]);
        const float4 b0 = *reinterpret_cast<const float4*>(&Bt[kk * 128 + tx * 8]);
        const float4 b1 = *reinterpret_cast<const float4*>(&Bt[kk * 128 + tx * 8 + 4]);
        const float av[4] = {a.x, a.y, a.z, a.w};
        const float bv[8] = {b0.x, b0.y, b0.z, b0.w, b1.x, b1.y, b1.z, b1.w};
#pragma unroll
        for (int i = 0; i < 4; ++i)
#pragma unroll
          for (int j = 0; j < 8; ++j)
            acc[i][j] += (double)av[i] * (double)bv[j];
      }
    }
    // epilogue: fp32 chain identical to reference, then register top-5
    float sj[8];
#pragma unroll
    for (int j = 0; j < 8; ++j) sj[j] = sq[c0 + tx * 8 + j];
#pragma unroll
    for (int i = 0; i < 4; ++i) {
#pragma unroll
      for (int j = 0; j < 8; ++j) {
        const float d2 = (si[i] + sj[j]) - 2.0f * (float)acc[i][j];
        const float d  = (float)sqrt((double)fmaxf(d2, 0.0f));
        const int  jj  = c0 + tx * 8 + j;
        INSERT5(td[i], ti[i], d, jj);
      }
    }
  }

  // block-level merge: 16 column-slice lists of 5 per row -> top-5 per row-quarter
  __syncthreads();                                  // everyone done with At/Bt
  float* cd = reinterpret_cast<float*>(raw);        // [80][64]
  int*   ci = reinterpret_cast<int*>(raw) + 80 * 64;
#pragma unroll
  for (int i = 0; i < 4; ++i)
#pragma unroll
    for (int s = 0; s < 5; ++s) {
      cd[(tx * 5 + s) * 64 + (ty * 4 + i)] = td[i][s];
      ci[(tx * 5 + s) * 64 + (ty * 4 + i)] = ti[i][s];
    }
  __syncthreads();
  if (tid < 64) {
    const int row = tid;
    float ld = -1.0f; int li = -1;
    for (int s = 0; s < 5; ++s) {
      float bd = 1e30f; int bi = 0x7fffffff;
      for (int c = 0; c < 80; ++c) {
        const float d = cd[c * 64 + row];
        const int   ix = ci[c * 64 + row];
        const bool gt_last = (d > ld) || (d == ld && ix > li);
        const bool lt_best = (d < bd) || (d == bd && ix < bi);
        if (gt_last && lt_best) { bd = d; bi = ix; }
      }
      ld = bd; li = bi;
      wsf[WS_PD + ((size_t)(r0 + row) * 4 + colq) * 5 + s] = bd;
      reinterpret_cast<int*>(wsf)[WS_PI + ((size_t)(r0 + row) * 4 + colq) * 5 + s] = bi;
    }
  }
}

// ---------------- kernel 2: 4-way merge + threefry + generate rows -------
__global__ __launch_bounds__(256) void gen_kernel(const float* __restrict__ X,
                                                  const float* __restrict__ wsf,
                                                  float* __restrict__ out) {
  __shared__ int   nbr_s[32][4];
  __shared__ float u_s[64];
  __shared__ int   nb_s[64];
  const float* Xm = X + (size_t)NMAJ * DIM;
  const int r0 = blockIdx.x * 32;
  const int tid = threadIdx.x;

  if (tid < 32) {
    const int row = r0 + tid;
    const float* pd = wsf + WS_PD + (size_t)row * 20;
    const int*   pi = reinterpret_cast<const int*>(wsf) + WS_PI + (size_t)row * 20;
    float ld = -1.0f; int li = -1;
    for (int s = 0; s < 5; ++s) {       // rank 0 = self (d ~ 0), ranks 1..4 = nbrs
      float bd = 1e30f; int bi = 0x7fffffff;
      for (int c = 0; c < 20; ++c) {
        const float d = pd[c]; const int ix = pi[c];
        const bool gt_last = (d > ld) || (d == ld && ix > li);
        const bool lt_best = (d < bd) || (d == bd && ix < bi);
        if (gt_last && lt_best) { bd = d; bi = ix; }
      }
      ld = bd; li = bi;
      if (s >= 1) nbr_s[tid][s - 1] = bi;
    }
  }
  __syncthreads();
  if (tid < 64) {
    uint2 k2, k2i;
    derive_keys(k2, k2i);
    const uint32_t f = (uint32_t)(2 * r0 + tid);      // flat index into (8192,2)
    const uint32_t ch = jax_bits(k2i, f) & 3u;        // randint(0,4)
    nb_s[tid] = nbr_s[tid >> 1][ch];
    const uint32_t ub = jax_bits(k2, f);
    u_s[tid] = __uint_as_float((ub >> 9) | 0x3f800000u) - 1.0f;
  }
  __syncthreads();

  const int c = tid * 2;
  for (int g = 0; g < 64; ++g) {
    const int i = g >> 1;
    const float u = u_s[g];
    const int nb = nb_s[g];
    float2 bv = *reinterpret_cast<const float2*>(Xm + (size_t)(r0 + i) * DIM + c);
    float2 nv = *reinterpret_cast<const float2*>(Xm + (size_t)nb * DIM + c);
    float2 o;
    o.x = bv.x + u * (nv.x - bv.x);
    o.y = bv.y + u * (nv.y - bv.y);
    *reinterpret_cast<float2*>(out + ((size_t)(NTOT + 2 * r0 + g)) * DIM + c) = o;
  }
}

// ---------------- kernel 3: passthrough X + y_out -----------------------
__global__ __launch_bounds__(256) void copy_kernel(const float* __restrict__ X,
                                                   const int* __restrict__ y,
                                                   float* __restrict__ out) {
  const long long XF4 = (long long)NTOT * DIM / 4;   // 4194304
  const long long YF4 = XROWS / 4;                   // 12288
  long long idx = (long long)blockIdx.x * blockDim.x + threadIdx.x;
  const long long stride = (long long)gridDim.x * blockDim.x;
  for (long long i = idx; i < XF4 + YF4; i += stride) {
    if (i < XF4) {
      reinterpret_cast<float4*>(out)[i] = reinterpret_cast<const float4*>(X)[i];
    } else {
      long long j = i - XF4;
      float4 o;
      if (j < NTOT / 4) {
        int4 yv = reinterpret_cast<const int4*>(y)[j];
        o.x = (float)yv.x; o.y = (float)yv.y; o.z = (float)yv.z; o.w = (float)yv.w;
      } else {
        o.x = o.y = o.z = o.w = 1.0f;
      }
      reinterpret_cast<float4*>(out + Y_OFF)[j] = o;
    }
  }
}

extern "C" void kernel_launch(void* const* d_in, const int* in_sizes, int n_in,
                              void* d_out, int out_size, void* d_ws, size_t ws_size,
                              hipStream_t stream) {
  const float* X = (const float*)d_in[0];
  const int*   y = (const int*)d_in[1];
  float* out = (float*)d_out;
  float* wsf = (float*)d_ws;
  (void)in_sizes; (void)n_in; (void)out_size; (void)ws_size;

  sq_kernel  <<<dim3(NMIN / 4), dim3(256), 0, stream>>>(X, wsf);
  smote_main <<<dim3(512),      dim3(256), 0, stream>>>(X, wsf);
  gen_kernel <<<dim3(NMIN / 32), dim3(256), 0, stream>>>(X, wsf, out);
  copy_kernel<<<dim3(2048),     dim3(256), 0, stream>>>(X, y, out);
}

// Round 3
// 1432.432 us; speedup vs baseline: 3.7637x; 1.4371x over previous
//
#include <hip/hip_runtime.h>
#include <stdint.h>
#include <math.h>

// JAX PRNG mode: 1 = threefry_partitionable (JAX >= 0.4.36 default), 0 = legacy/original.
#ifndef JAX_PARTITIONABLE
#define JAX_PARTITIONABLE 1
#endif

#define DIM    512
#define NTOT   32768
#define NMAJ   24576
#define NMIN   8192
#define NGEN   16384                       // NMIN * 2
#define XROWS  49152                       // NTOT + NGEN
#define Y_OFF  ((size_t)XROWS * DIM)       // 25165824

// ws layout (4-byte units): [0,8192) sq fp32 ; [8192, +8192*64) cand ints ; then nbr ints
#define WS_CAND  (NMIN)
#define WS_NBR   (NMIN + NMIN * 64)

// ---------------- threefry2x32 (Random123 / JAX schedule) ----------------
__device__ __forceinline__ void tf2x32(uint32_t k0, uint32_t k1,
                                       uint32_t x0, uint32_t x1,
                                       uint32_t &o0, uint32_t &o1) {
  const uint32_t ks2 = k0 ^ k1 ^ 0x1BD11BDAu;
  x0 += k0; x1 += k1;
#define TF_R(r) { x0 += x1; x1 = (x1 << (r)) | (x1 >> (32 - (r))); x1 ^= x0; }
  TF_R(13) TF_R(15) TF_R(26) TF_R(6)
  x0 += k1;  x1 += ks2 + 1u;
  TF_R(17) TF_R(29) TF_R(16) TF_R(24)
  x0 += ks2; x1 += k0 + 2u;
  TF_R(13) TF_R(15) TF_R(26) TF_R(6)
  x0 += k0;  x1 += k1 + 3u;
  TF_R(17) TF_R(29) TF_R(16) TF_R(24)
  x0 += k1;  x1 += ks2 + 4u;
  TF_R(13) TF_R(15) TF_R(26) TF_R(6)
  x0 += ks2; x1 += k0 + 5u;
#undef TF_R
  o0 = x0; o1 = x1;
}

#if JAX_PARTITIONABLE
__device__ __forceinline__ void jax_split(uint2 key, uint2 &c0, uint2 &c1) {
  tf2x32(key.x, key.y, 0u, 0u, c0.x, c0.y);
  tf2x32(key.x, key.y, 0u, 1u, c1.x, c1.y);
}
__device__ __forceinline__ uint32_t jax_bits(uint2 key, uint32_t f) {
  uint32_t a, b;
  tf2x32(key.x, key.y, 0u, f, a, b);
  return a ^ b;
}
#else
__device__ __forceinline__ void jax_split(uint2 key, uint2 &c0, uint2 &c1) {
  uint32_t a0, b0, a1, b1;
  tf2x32(key.x, key.y, 0u, 2u, a0, b0);
  tf2x32(key.x, key.y, 1u, 3u, a1, b1);
  c0 = make_uint2(a0, a1);
  c1 = make_uint2(b0, b1);
}
__device__ __forceinline__ uint32_t jax_bits(uint2 key, uint32_t f) {
  uint32_t a, b;
  if (f < (NGEN / 2)) { tf2x32(key.x, key.y, f, f + NGEN / 2, a, b); return a; }
  tf2x32(key.x, key.y, f - NGEN / 2, f, a, b); return b;
}
#endif

__device__ __forceinline__ void derive_keys(uint2 &k2, uint2 &k2i) {
  uint2 root = make_uint2(0u, 42u);
  uint2 dead, sub, k1;
  jax_split(root, dead, sub);
  jax_split(sub, k1, k2);
  jax_split(k1, dead, k2i);
}

// ---------------- kernel 0: minority row squared norms (fp64 -> fp32) ----
__global__ __launch_bounds__(256) void sq_kernel(const float* __restrict__ X,
                                                 float* __restrict__ wsf) {
  const int row  = blockIdx.x * 4 + (threadIdx.x >> 6);
  const int lane = threadIdx.x & 63;
  const float* Xm = X + (size_t)NMAJ * DIM;
  const float4* p = reinterpret_cast<const float4*>(Xm + (size_t)row * DIM);
  double s = 0.0;
#pragma unroll
  for (int q = 0; q < 2; ++q) {
    float4 v = p[lane + q * 64];
    s += (double)v.x * v.x + (double)v.y * v.y + (double)v.z * v.z + (double)v.w * v.w;
  }
#pragma unroll
  for (int off = 32; off > 0; off >>= 1) s += __shfl_down(s, off);
  if (lane == 0) wsf[row] = (float)s;
}

// strict-< 5-deep insertion (ascending j within a thread => stable order)
#define INSERT5(TD, TI, dv, jv)                                          \
  if ((dv) < TD[4]) {                                                    \
    if ((dv) < TD[3]) { TD[4]=TD[3]; TI[4]=TI[3];                        \
      if ((dv) < TD[2]) { TD[3]=TD[2]; TI[3]=TI[2];                      \
        if ((dv) < TD[1]) { TD[2]=TD[1]; TI[2]=TI[1];                    \
          if ((dv) < TD[0]) { TD[1]=TD[0]; TI[1]=TI[0]; TD[0]=(dv); TI[0]=(jv); } \
          else { TD[1]=(dv); TI[1]=(jv); } }                             \
        else { TD[2]=(dv); TI[2]=(jv); } }                               \
      else { TD[3]=(dv); TI[3]=(jv); } }                                 \
    else { TD[4]=(dv); TI[4]=(jv); } }

// B-tile LDS swizzle: 16B chunk c -> c ^ ((c>>4)&1)  (2-way banks on read & write)
__device__ __forceinline__ int bswz(int col) {
  int c = col >> 2;
  c ^= (c >> 4) & 1;
  return c * 4 + (col & 3);
}

// ---------------- kernel 1: fp32 approx syrk + candidate top-8/eighth ----
// grid = 1024: e = bid&7 (col eighth, 1024 cols), rowg = bid>>3 (64 rows)
__global__ __launch_bounds__(256, 2) void smote_main(const float* __restrict__ X,
                                                     float* __restrict__ wsf) {
  __shared__ __align__(16) char raw[40960];
  float* At = reinterpret_cast<float*>(raw);        // [32][64]  k-major
  float* Bt = At + 32 * 64;                         // [32][128] k-major, swizzled

  const float* Xm = X + (size_t)NMAJ * DIM;
  const int e    = blockIdx.x & 7;
  const int rowg = blockIdx.x >> 3;
  const int r0 = rowg * 64;
  const int cb = e * 1024;
  const int tid = threadIdx.x;
  const int ty = tid >> 4;      // 0..15 -> rows ty*4..+3
  const int tx = tid & 15;      // 0..15 -> cols tx*8..+7

  const int pb0 = bswz(tx * 8);       // chunk-aligned float index
  const int pb1 = bswz(tx * 8 + 4);

  // staging decomposition (per kt): A 2x float4, B 4x float4
  const int sr   = tid & 63;          // A row / B col(lane)
  const int sk   = tid >> 6;          // k-chunk base

  float td[4][5];
  int   ti[4][5];
#pragma unroll
  for (int i = 0; i < 4; ++i)
#pragma unroll
    for (int s = 0; s < 5; ++s) { td[i][s] = 1e30f; ti[i][s] = 0x7fffffff; }

  for (int ct = 0; ct < 8; ++ct) {
    const int c0 = cb + ct * 128;
    float acc[4][8];
#pragma unroll
    for (int i = 0; i < 4; ++i)
#pragma unroll
      for (int j = 0; j < 8; ++j) acc[i][j] = 0.0f;

    // prefetch kt=0 into registers
    float4 pa[2], pb[4];
#pragma unroll
    for (int q = 0; q < 2; ++q)
      pa[q] = *reinterpret_cast<const float4*>(Xm + (size_t)(r0 + sr) * DIM + (sk + 4 * q) * 4);
#pragma unroll
    for (int q = 0; q < 4; ++q)
      pb[q] = *reinterpret_cast<const float4*>(Xm + (size_t)(c0 + sr + 64 * (q & 1)) * DIM + (sk + 4 * (q >> 1)) * 4);

    for (int kt = 0; kt < 16; ++kt) {
      __syncthreads();                 // previous compute done; LDS free
      // store regs -> LDS
#pragma unroll
      for (int q = 0; q < 2; ++q) {
        const int kb = 4 * (sk + 4 * q);
        At[(kb + 0) * 64 + sr] = pa[q].x;
        At[(kb + 1) * 64 + sr] = pa[q].y;
        At[(kb + 2) * 64 + sr] = pa[q].z;
        At[(kb + 3) * 64 + sr] = pa[q].w;
      }
#pragma unroll
      for (int q = 0; q < 4; ++q) {
        const int kb = 4 * (sk + 4 * (q >> 1));
        const int sc = bswz(sr + 64 * (q & 1));
        Bt[(kb + 0) * 128 + sc] = pb[q].x;
        Bt[(kb + 1) * 128 + sc] = pb[q].y;
        Bt[(kb + 2) * 128 + sc] = pb[q].z;
        Bt[(kb + 3) * 128 + sc] = pb[q].w;
      }
      // prefetch next k-tile (overlaps with compute below)
      if (kt < 15) {
        const int k0n = (kt + 1) * 32;
#pragma unroll
        for (int q = 0; q < 2; ++q)
          pa[q] = *reinterpret_cast<const float4*>(Xm + (size_t)(r0 + sr) * DIM + k0n + (sk + 4 * q) * 4);
#pragma unroll
        for (int q = 0; q < 4; ++q)
          pb[q] = *reinterpret_cast<const float4*>(Xm + (size_t)(c0 + sr + 64 * (q & 1)) * DIM + k0n + (sk + 4 * (q >> 1)) * 4);
      }
      __syncthreads();
#pragma unroll 8
      for (int kk = 0; kk < 32; ++kk) {
        const float4 a  = *reinterpret_cast<const float4*>(&At[kk * 64 + ty * 4]);
        const float4 b0 = *reinterpret_cast<const float4*>(&Bt[kk * 128 + pb0]);
        const float4 b1 = *reinterpret_cast<const float4*>(&Bt[kk * 128 + pb1]);
        const float av[4] = {a.x, a.y, a.z, a.w};
        const float bv[8] = {b0.x, b0.y, b0.z, b0.w, b1.x, b1.y, b1.z, b1.w};
#pragma unroll
        for (int i = 0; i < 4; ++i)
#pragma unroll
          for (int j = 0; j < 8; ++j)
            acc[i][j] += av[i] * bv[j];
      }
    }
    // epilogue: selection metric m = sq[j] - 2*dot  (row-constant sq[i], sqrt dropped)
    const float4 s0 = *reinterpret_cast<const float4*>(&wsf[c0 + tx * 8]);
    const float4 s1 = *reinterpret_cast<const float4*>(&wsf[c0 + tx * 8 + 4]);
    const float sj[8] = {s0.x, s0.y, s0.z, s0.w, s1.x, s1.y, s1.z, s1.w};
#pragma unroll
    for (int i = 0; i < 4; ++i) {
#pragma unroll
      for (int j = 0; j < 8; ++j) {
        const float m = sj[j] - 2.0f * acc[i][j];
        const int  jj = c0 + tx * 8 + j;
        INSERT5(td[i], ti[i], m, jj);
      }
    }
  }

  // block merge: 16 slice-lists of 5 per row -> top-8 per row for this eighth
  __syncthreads();
  float* cd = reinterpret_cast<float*>(raw);        // [80][64]
  int*   ci = reinterpret_cast<int*>(raw) + 80 * 64;
#pragma unroll
  for (int i = 0; i < 4; ++i)
#pragma unroll
    for (int s = 0; s < 5; ++s) {
      cd[(tx * 5 + s) * 64 + (ty * 4 + i)] = td[i][s];
      ci[(tx * 5 + s) * 64 + (ty * 4 + i)] = ti[i][s];
    }
  __syncthreads();
  if (tid < 64) {
    const int row = tid;
    int* cand = reinterpret_cast<int*>(wsf) + WS_CAND + (size_t)(r0 + row) * 64 + e * 8;
    float ld = -1e31f; int li = -1;
    for (int s = 0; s < 8; ++s) {
      float bd = 1e30f; int bi = 0x7fffffff;
      for (int c = 0; c < 80; ++c) {
        const float d = cd[c * 64 + row];
        const int  ix = ci[c * 64 + row];
        const bool gt_last = (d > ld) || (d == ld && ix > li);
        const bool lt_best = (d < bd) || (d == bd && ix < bi);
        if (gt_last && lt_best) { bd = d; bi = ix; }
      }
      ld = bd; li = bi;
      cand[s] = bi;
    }
  }
}

// ---------------- kernel 2: exact fp64 rerank of 64 candidates per row ---
__global__ __launch_bounds__(256) void rerank_kernel(const float* __restrict__ X,
                                                     float* __restrict__ wsf) {
  __shared__ float dd[64];
  __shared__ int   ii[64];
  const float* Xm = X + (size_t)NMAJ * DIM;
  const int row  = blockIdx.x;
  const int tid  = threadIdx.x;
  const int wave = tid >> 6;
  const int lane = tid & 63;
  const int* cand = reinterpret_cast<const int*>(wsf) + WS_CAND + (size_t)row * 64;
  const float si = wsf[row];
  const float4* Xi = reinterpret_cast<const float4*>(Xm + (size_t)row * DIM);

  for (int c = wave; c < 64; c += 4) {
    const int j = cand[c];
    const float4* Xj = reinterpret_cast<const float4*>(Xm + (size_t)j * DIM);
    double s = 0.0;
#pragma unroll
    for (int q = 0; q < 2; ++q) {
      const float4 xi = Xi[lane + 64 * q];
      const float4 xj = Xj[lane + 64 * q];
      s += (double)xi.x * xj.x + (double)xi.y * xj.y
         + (double)xi.z * xj.z + (double)xi.w * xj.w;
    }
#pragma unroll
    for (int off = 32; off > 0; off >>= 1) s += __shfl_down(s, off);
    if (lane == 0) {
      const float d2 = (si + wsf[j]) - 2.0f * (float)s;   // reference fp32 chain
      dd[c] = (float)sqrt((double)fmaxf(d2, 0.0f));       // correctly-rounded sqrt
      ii[c] = j;
    }
  }
  __syncthreads();
  if (tid == 0) {
    int* nbr = reinterpret_cast<int*>(wsf) + WS_NBR + (size_t)row * 4;
    float ld = -1.0f; int li = -1;
    for (int s = 0; s < 5; ++s) {        // rank 0 = self (D == 0)
      float bd = 1e30f; int bi = 0x7fffffff;
      for (int c = 0; c < 64; ++c) {
        const float d = dd[c]; const int ix = ii[c];
        const bool gt_last = (d > ld) || (d == ld && ix > li);
        const bool lt_best = (d < bd) || (d == bd && ix < bi);
        if (gt_last && lt_best) { bd = d; bi = ix; }
      }
      ld = bd; li = bi;
      if (s >= 1) nbr[s - 1] = bi;
    }
  }
}

// ---------------- kernel 3: threefry + generate rows ---------------------
__global__ __launch_bounds__(256) void gen_kernel(const float* __restrict__ X,
                                                  const float* __restrict__ wsf,
                                                  float* __restrict__ out) {
  __shared__ int   nbr_s[32][4];
  __shared__ float u_s[64];
  __shared__ int   nb_s[64];
  const float* Xm = X + (size_t)NMAJ * DIM;
  const int r0 = blockIdx.x * 32;
  const int tid = threadIdx.x;

  if (tid < 32) {
    const int* nb = reinterpret_cast<const int*>(wsf) + WS_NBR + (size_t)(r0 + tid) * 4;
#pragma unroll
    for (int s = 0; s < 4; ++s) nbr_s[tid][s] = nb[s];
  }
  __syncthreads();
  if (tid < 64) {
    uint2 k2, k2i;
    derive_keys(k2, k2i);
    const uint32_t f = (uint32_t)(2 * r0 + tid);      // flat index into (8192,2)
    const uint32_t ch = jax_bits(k2i, f) & 3u;        // randint(0,4)
    nb_s[tid] = nbr_s[tid >> 1][ch];
    const uint32_t ub = jax_bits(k2, f);
    u_s[tid] = __uint_as_float((ub >> 9) | 0x3f800000u) - 1.0f;
  }
  __syncthreads();

  const int c = tid * 2;
  for (int g = 0; g < 64; ++g) {
    const int i = g >> 1;
    const float u = u_s[g];
    const int nb = nb_s[g];
    float2 bv = *reinterpret_cast<const float2*>(Xm + (size_t)(r0 + i) * DIM + c);
    float2 nv = *reinterpret_cast<const float2*>(Xm + (size_t)nb * DIM + c);
    float2 o;
    o.x = bv.x + u * (nv.x - bv.x);
    o.y = bv.y + u * (nv.y - bv.y);
    *reinterpret_cast<float2*>(out + ((size_t)(NTOT + 2 * r0 + g)) * DIM + c) = o;
  }
}

// ---------------- kernel 4: passthrough X + y_out -----------------------
__global__ __launch_bounds__(256) void copy_kernel(const float* __restrict__ X,
                                                   const int* __restrict__ y,
                                                   float* __restrict__ out) {
  const long long XF4 = (long long)NTOT * DIM / 4;   // 4194304
  const long long YF4 = XROWS / 4;                   // 12288
  long long idx = (long long)blockIdx.x * blockDim.x + threadIdx.x;
  const long long stride = (long long)gridDim.x * blockDim.x;
  for (long long i = idx; i < XF4 + YF4; i += stride) {
    if (i < XF4) {
      reinterpret_cast<float4*>(out)[i] = reinterpret_cast<const float4*>(X)[i];
    } else {
      long long j = i - XF4;
      float4 o;
      if (j < NTOT / 4) {
        int4 yv = reinterpret_cast<const int4*>(y)[j];
        o.x = (float)yv.x; o.y = (float)yv.y; o.z = (float)yv.z; o.w = (float)yv.w;
      } else {
        o.x = o.y = o.z = o.w = 1.0f;
      }
      reinterpret_cast<float4*>(out + Y_OFF)[j] = o;
    }
  }
}

extern "C" void kernel_launch(void* const* d_in, const int* in_sizes, int n_in,
                              void* d_out, int out_size, void* d_ws, size_t ws_size,
                              hipStream_t stream) {
  const float* X = (const float*)d_in[0];
  const int*   y = (const int*)d_in[1];
  float* out = (float*)d_out;
  float* wsf = (float*)d_ws;
  (void)in_sizes; (void)n_in; (void)out_size; (void)ws_size;

  sq_kernel    <<<dim3(NMIN / 4),  dim3(256), 0, stream>>>(X, wsf);
  smote_main   <<<dim3(1024),      dim3(256), 0, stream>>>(X, wsf);
  rerank_kernel<<<dim3(NMIN),      dim3(256), 0, stream>>>(X, wsf);
  gen_kernel   <<<dim3(NMIN / 32), dim3(256), 0, stream>>>(X, wsf, out);
  copy_kernel  <<<dim3(2048),      dim3(256), 0, stream>>>(X, y, out);
}

// Round 4
// 1329.430 us; speedup vs baseline: 4.0553x; 1.0775x over previous
//
#include <hip/hip_runtime.h>
#include <stdint.h>
#include <math.h>

// JAX PRNG mode: 1 = threefry_partitionable (JAX >= 0.4.36 default), 0 = legacy/original.
#ifndef JAX_PARTITIONABLE
#define JAX_PARTITIONABLE 1
#endif

#define DIM    512
#define NTOT   32768
#define NMAJ   24576
#define NMIN   8192
#define NGEN   16384                       // NMIN * 2
#define XROWS  49152                       // NTOT + NGEN
#define Y_OFF  ((size_t)XROWS * DIM)       // 25165824

// ws layout (4-byte units): [0,8192) sq fp32 ; [8192, +8192*64) cand ints ; then nbr ints
#define WS_CAND  (NMIN)
#define WS_NBR   (NMIN + NMIN * 64)

// ---------------- threefry2x32 (Random123 / JAX schedule) ----------------
__device__ __forceinline__ void tf2x32(uint32_t k0, uint32_t k1,
                                       uint32_t x0, uint32_t x1,
                                       uint32_t &o0, uint32_t &o1) {
  const uint32_t ks2 = k0 ^ k1 ^ 0x1BD11BDAu;
  x0 += k0; x1 += k1;
#define TF_R(r) { x0 += x1; x1 = (x1 << (r)) | (x1 >> (32 - (r))); x1 ^= x0; }
  TF_R(13) TF_R(15) TF_R(26) TF_R(6)
  x0 += k1;  x1 += ks2 + 1u;
  TF_R(17) TF_R(29) TF_R(16) TF_R(24)
  x0 += ks2; x1 += k0 + 2u;
  TF_R(13) TF_R(15) TF_R(26) TF_R(6)
  x0 += k0;  x1 += k1 + 3u;
  TF_R(17) TF_R(29) TF_R(16) TF_R(24)
  x0 += k1;  x1 += ks2 + 4u;
  TF_R(13) TF_R(15) TF_R(26) TF_R(6)
  x0 += ks2; x1 += k0 + 5u;
#undef TF_R
  o0 = x0; o1 = x1;
}

#if JAX_PARTITIONABLE
__device__ __forceinline__ void jax_split(uint2 key, uint2 &c0, uint2 &c1) {
  tf2x32(key.x, key.y, 0u, 0u, c0.x, c0.y);
  tf2x32(key.x, key.y, 0u, 1u, c1.x, c1.y);
}
__device__ __forceinline__ uint32_t jax_bits(uint2 key, uint32_t f) {
  uint32_t a, b;
  tf2x32(key.x, key.y, 0u, f, a, b);
  return a ^ b;
}
#else
__device__ __forceinline__ void jax_split(uint2 key, uint2 &c0, uint2 &c1) {
  uint32_t a0, b0, a1, b1;
  tf2x32(key.x, key.y, 0u, 2u, a0, b0);
  tf2x32(key.x, key.y, 1u, 3u, a1, b1);
  c0 = make_uint2(a0, a1);
  c1 = make_uint2(b0, b1);
}
__device__ __forceinline__ uint32_t jax_bits(uint2 key, uint32_t f) {
  uint32_t a, b;
  if (f < (NGEN / 2)) { tf2x32(key.x, key.y, f, f + NGEN / 2, a, b); return a; }
  tf2x32(key.x, key.y, f - NGEN / 2, f, a, b); return b;
}
#endif

__device__ __forceinline__ void derive_keys(uint2 &k2, uint2 &k2i) {
  uint2 root = make_uint2(0u, 42u);
  uint2 dead, sub, k1;
  jax_split(root, dead, sub);
  jax_split(sub, k1, k2);
  jax_split(k1, dead, k2i);
}

// ---------------- kernel 0: minority row squared norms (fp64 -> fp32) ----
__global__ __launch_bounds__(256) void sq_kernel(const float* __restrict__ X,
                                                 float* __restrict__ wsf) {
  const int row  = blockIdx.x * 4 + (threadIdx.x >> 6);
  const int lane = threadIdx.x & 63;
  const float* Xm = X + (size_t)NMAJ * DIM;
  const float4* p = reinterpret_cast<const float4*>(Xm + (size_t)row * DIM);
  double s = 0.0;
#pragma unroll
  for (int q = 0; q < 2; ++q) {
    float4 v = p[lane + q * 64];
    s += (double)v.x * v.x + (double)v.y * v.y + (double)v.z * v.z + (double)v.w * v.w;
  }
#pragma unroll
  for (int off = 32; off > 0; off >>= 1) s += __shfl_down(s, off);
  if (lane == 0) wsf[row] = (float)s;
}

// strict-< 5-deep insertion (ascending j within a thread => stable order)
#define INSERT5(TD, TI, dv, jv)                                          \
  if ((dv) < TD[4]) {                                                    \
    if ((dv) < TD[3]) { TD[4]=TD[3]; TI[4]=TI[3];                        \
      if ((dv) < TD[2]) { TD[3]=TD[2]; TI[3]=TI[2];                      \
        if ((dv) < TD[1]) { TD[2]=TD[1]; TI[2]=TI[1];                    \
          if ((dv) < TD[0]) { TD[1]=TD[0]; TI[1]=TI[0]; TD[0]=(dv); TI[0]=(jv); } \
          else { TD[1]=(dv); TI[1]=(jv); } }                             \
        else { TD[2]=(dv); TI[2]=(jv); } }                               \
      else { TD[3]=(dv); TI[3]=(jv); } }                                 \
    else { TD[4]=(dv); TI[4]=(jv); } }

// LDS swizzle for 128-float rows: 16B chunk c -> c ^ (c>>4).
// Reads (16 unique chunks, even or odd set) and writes (8 consecutive chunks
// x 4 sub-rows x 2 k) both land at exactly 2-way bank aliasing (free, m136).
__device__ __forceinline__ int aswz(int r) {
  int c = r >> 2;
  c ^= (c >> 4);
  return c * 4 + (r & 3);
}

// ---------------- kernel 1: fp32 approx syrk + candidate top-8/eighth ----
// 128x128 block tile, BK=32, 8x8 thread tile.
// grid = 512: e = bid&7 (col eighth, 1024 cols), rowg = bid>>3 (128 rows)
__global__ __launch_bounds__(256) void smote_main(const float* __restrict__ X,
                                                  float* __restrict__ wsf) {
  __shared__ __align__(16) char raw[40960];
  float* At = reinterpret_cast<float*>(raw);        // [32][128] k-major, swizzled
  float* Bt = At + 32 * 128;                        // [32][128] k-major, swizzled

  const float* Xm = X + (size_t)NMAJ * DIM;
  const int e    = blockIdx.x & 7;
  const int rowg = blockIdx.x >> 3;
  const int r0 = rowg * 128;
  const int cb = e * 1024;
  const int tid = threadIdx.x;
  const int ty = tid >> 4;      // 0..15 -> rows ty*8..+7
  const int tx = tid & 15;      // 0..15 -> cols tx*8..+7

  // read offsets (chunk-aligned, 16B)
  const int ra0 = aswz(ty * 8), ra1 = aswz(ty * 8 + 4);
  const int rb0 = aswz(tx * 8), rb1 = aswz(tx * 8 + 4);

  // staging: each thread owns row sr (one A row AND one B col), 16 k-floats
  const int sr    = tid >> 1;          // 0..127
  const int skb   = (tid & 1) * 16;    // k sub-offset
  const int sbase = aswz(sr);          // swizzled column within a k-line

  float td[8][5];
  int   ti[8][5];
#pragma unroll
  for (int i = 0; i < 8; ++i)
#pragma unroll
    for (int s = 0; s < 5; ++s) { td[i][s] = 1e30f; ti[i][s] = 0x7fffffff; }

  for (int ct = 0; ct < 8; ++ct) {
    const int c0 = cb + ct * 128;
    float acc[8][8];
#pragma unroll
    for (int i = 0; i < 8; ++i)
#pragma unroll
      for (int j = 0; j < 8; ++j) acc[i][j] = 0.0f;

    // prefetch kt=0 into registers: A row + B col, 4 float4 each
    float4 pf[8];
#pragma unroll
    for (int q = 0; q < 4; ++q)
      pf[q] = *reinterpret_cast<const float4*>(Xm + (size_t)(r0 + sr) * DIM + skb + q * 4);
#pragma unroll
    for (int q = 0; q < 4; ++q)
      pf[4 + q] = *reinterpret_cast<const float4*>(Xm + (size_t)(c0 + sr) * DIM + skb + q * 4);

    for (int kt = 0; kt < 16; ++kt) {
      __syncthreads();                 // previous compute done; LDS free
      // store regs -> LDS (k-major, swizzled). 2-way banks (free).
#pragma unroll
      for (int q = 0; q < 4; ++q) {
        const int kb = skb + q * 4;
        At[(kb + 0) * 128 + sbase] = pf[q].x;
        At[(kb + 1) * 128 + sbase] = pf[q].y;
        At[(kb + 2) * 128 + sbase] = pf[q].z;
        At[(kb + 3) * 128 + sbase] = pf[q].w;
        Bt[(kb + 0) * 128 + sbase] = pf[4 + q].x;
        Bt[(kb + 1) * 128 + sbase] = pf[4 + q].y;
        Bt[(kb + 2) * 128 + sbase] = pf[4 + q].z;
        Bt[(kb + 3) * 128 + sbase] = pf[4 + q].w;
      }
      // prefetch next k-tile (in flight across the compute phase)
      if (kt < 15) {
        const int k0n = (kt + 1) * 32 + skb;
#pragma unroll
        for (int q = 0; q < 4; ++q)
          pf[q] = *reinterpret_cast<const float4*>(Xm + (size_t)(r0 + sr) * DIM + k0n + q * 4);
#pragma unroll
        for (int q = 0; q < 4; ++q)
          pf[4 + q] = *reinterpret_cast<const float4*>(Xm + (size_t)(c0 + sr) * DIM + k0n + q * 4);
      }
      __syncthreads();
#pragma unroll 4
      for (int kk = 0; kk < 32; ++kk) {
        const float4 a0 = *reinterpret_cast<const float4*>(&At[kk * 128 + ra0]);
        const float4 a1 = *reinterpret_cast<const float4*>(&At[kk * 128 + ra1]);
        const float4 b0 = *reinterpret_cast<const float4*>(&Bt[kk * 128 + rb0]);
        const float4 b1 = *reinterpret_cast<const float4*>(&Bt[kk * 128 + rb1]);
        const float av[8] = {a0.x, a0.y, a0.z, a0.w, a1.x, a1.y, a1.z, a1.w};
        const float bv[8] = {b0.x, b0.y, b0.z, b0.w, b1.x, b1.y, b1.z, b1.w};
#pragma unroll
        for (int i = 0; i < 8; ++i)
#pragma unroll
          for (int j = 0; j < 8; ++j)
            acc[i][j] += av[i] * bv[j];
      }
    }
    // epilogue: selection metric m = sq[j] - 2*dot (row-constant sq[i], sqrt dropped)
    const float4 s0 = *reinterpret_cast<const float4*>(&wsf[c0 + tx * 8]);
    const float4 s1 = *reinterpret_cast<const float4*>(&wsf[c0 + tx * 8 + 4]);
    const float sj[8] = {s0.x, s0.y, s0.z, s0.w, s1.x, s1.y, s1.z, s1.w};
#pragma unroll
    for (int i = 0; i < 8; ++i) {
#pragma unroll
      for (int j = 0; j < 8; ++j) {
        const float m = sj[j] - 2.0f * acc[i][j];
        const int  jj = c0 + tx * 8 + j;
        INSERT5(td[i], ti[i], m, jj);
      }
    }
  }

  // block merge: per row, 16 slice-lists of 5 -> top-8 for this eighth.
  // Two half-passes of 64 rows to fit 40 KB (cd[80][64] + ci[80][64]).
  float* cd = reinterpret_cast<float*>(raw);
  int*   ci = reinterpret_cast<int*>(raw) + 80 * 64;
#pragma unroll
  for (int pass = 0; pass < 2; ++pass) {
    __syncthreads();                   // LDS free (compute done / prev pass read)
    if ((ty >> 3) == pass) {
#pragma unroll
      for (int i = 0; i < 8; ++i) {
        const int rl = ty * 8 + i - pass * 64;   // 0..63
#pragma unroll
        for (int s = 0; s < 5; ++s) {
          cd[(tx * 5 + s) * 64 + rl] = td[i][s];
          ci[(tx * 5 + s) * 64 + rl] = ti[i][s];
        }
      }
    }
    __syncthreads();
    if (tid < 64) {
      const int row = pass * 64 + tid;
      int* cand = reinterpret_cast<int*>(wsf) + WS_CAND + (size_t)(r0 + row) * 64 + e * 8;
      float ld = -1e31f; int li = -1;
      for (int s = 0; s < 8; ++s) {
        float bd = 1e30f; int bi = 0x7fffffff;
        for (int c = 0; c < 80; ++c) {
          const float d = cd[c * 64 + tid];
          const int  ix = ci[c * 64 + tid];
          const bool gt_last = (d > ld) || (d == ld && ix > li);
          const bool lt_best = (d < bd) || (d == bd && ix < bi);
          if (gt_last && lt_best) { bd = d; bi = ix; }
        }
        ld = bd; li = bi;
        cand[s] = bi;
      }
    }
  }
}

// ---------------- kernel 2: exact fp64 rerank of 64 candidates per row ---
__global__ __launch_bounds__(256) void rerank_kernel(const float* __restrict__ X,
                                                     float* __restrict__ wsf) {
  __shared__ float dd[64];
  __shared__ int   ii[64];
  const float* Xm = X + (size_t)NMAJ * DIM;
  const int row  = blockIdx.x;
  const int tid  = threadIdx.x;
  const int wave = tid >> 6;
  const int lane = tid & 63;
  const int* cand = reinterpret_cast<const int*>(wsf) + WS_CAND + (size_t)row * 64;
  const float si = wsf[row];
  const float4* Xi = reinterpret_cast<const float4*>(Xm + (size_t)row * DIM);

  for (int c = wave; c < 64; c += 4) {
    const int j = cand[c];
    const float4* Xj = reinterpret_cast<const float4*>(Xm + (size_t)j * DIM);
    double s = 0.0;
#pragma unroll
    for (int q = 0; q < 2; ++q) {
      const float4 xi = Xi[lane + 64 * q];
      const float4 xj = Xj[lane + 64 * q];
      s += (double)xi.x * xj.x + (double)xi.y * xj.y
         + (double)xi.z * xj.z + (double)xi.w * xj.w;
    }
#pragma unroll
    for (int off = 32; off > 0; off >>= 1) s += __shfl_down(s, off);
    if (lane == 0) {
      const float d2 = (si + wsf[j]) - 2.0f * (float)s;   // reference fp32 chain
      dd[c] = (float)sqrt((double)fmaxf(d2, 0.0f));       // correctly-rounded sqrt
      ii[c] = j;
    }
  }
  __syncthreads();
  if (tid == 0) {
    int* nbr = reinterpret_cast<int*>(wsf) + WS_NBR + (size_t)row * 4;
    float ld = -1.0f; int li = -1;
    for (int s = 0; s < 5; ++s) {        // rank 0 = self (D == 0)
      float bd = 1e30f; int bi = 0x7fffffff;
      for (int c = 0; c < 64; ++c) {
        const float d = dd[c]; const int ix = ii[c];
        const bool gt_last = (d > ld) || (d == ld && ix > li);
        const bool lt_best = (d < bd) || (d == bd && ix < bi);
        if (gt_last && lt_best) { bd = d; bi = ix; }
      }
      ld = bd; li = bi;
      if (s >= 1) nbr[s - 1] = bi;
    }
  }
}

// ---------------- kernel 3: threefry + generate rows ---------------------
__global__ __launch_bounds__(256) void gen_kernel(const float* __restrict__ X,
                                                  const float* __restrict__ wsf,
                                                  float* __restrict__ out) {
  __shared__ int   nbr_s[32][4];
  __shared__ float u_s[64];
  __shared__ int   nb_s[64];
  const float* Xm = X + (size_t)NMAJ * DIM;
  const int r0 = blockIdx.x * 32;
  const int tid = threadIdx.x;

  if (tid < 32) {
    const int* nb = reinterpret_cast<const int*>(wsf) + WS_NBR + (size_t)(r0 + tid) * 4;
#pragma unroll
    for (int s = 0; s < 4; ++s) nbr_s[tid][s] = nb[s];
  }
  __syncthreads();
  if (tid < 64) {
    uint2 k2, k2i;
    derive_keys(k2, k2i);
    const uint32_t f = (uint32_t)(2 * r0 + tid);      // flat index into (8192,2)
    const uint32_t ch = jax_bits(k2i, f) & 3u;        // randint(0,4)
    nb_s[tid] = nbr_s[tid >> 1][ch];
    const uint32_t ub = jax_bits(k2, f);
    u_s[tid] = __uint_as_float((ub >> 9) | 0x3f800000u) - 1.0f;
  }
  __syncthreads();

  const int c = tid * 2;
  for (int g = 0; g < 64; ++g) {
    const int i = g >> 1;
    const float u = u_s[g];
    const int nb = nb_s[g];
    float2 bv = *reinterpret_cast<const float2*>(Xm + (size_t)(r0 + i) * DIM + c);
    float2 nv = *reinterpret_cast<const float2*>(Xm + (size_t)nb * DIM + c);
    float2 o;
    o.x = bv.x + u * (nv.x - bv.x);
    o.y = bv.y + u * (nv.y - bv.y);
    *reinterpret_cast<float2*>(out + ((size_t)(NTOT + 2 * r0 + g)) * DIM + c) = o;
  }
}

// ---------------- kernel 4: passthrough X + y_out -----------------------
__global__ __launch_bounds__(256) void copy_kernel(const float* __restrict__ X,
                                                   const int* __restrict__ y,
                                                   float* __restrict__ out) {
  const long long XF4 = (long long)NTOT * DIM / 4;   // 4194304
  const long long YF4 = XROWS / 4;                   // 12288
  long long idx = (long long)blockIdx.x * blockDim.x + threadIdx.x;
  const long long stride = (long long)gridDim.x * blockDim.x;
  for (long long i = idx; i < XF4 + YF4; i += stride) {
    if (i < XF4) {
      reinterpret_cast<float4*>(out)[i] = reinterpret_cast<const float4*>(X)[i];
    } else {
      long long j = i - XF4;
      float4 o;
      if (j < NTOT / 4) {
        int4 yv = reinterpret_cast<const int4*>(y)[j];
        o.x = (float)yv.x; o.y = (float)yv.y; o.z = (float)yv.z; o.w = (float)yv.w;
      } else {
        o.x = o.y = o.z = o.w = 1.0f;
      }
      reinterpret_cast<float4*>(out + Y_OFF)[j] = o;
    }
  }
}

extern "C" void kernel_launch(void* const* d_in, const int* in_sizes, int n_in,
                              void* d_out, int out_size, void* d_ws, size_t ws_size,
                              hipStream_t stream) {
  const float* X = (const float*)d_in[0];
  const int*   y = (const int*)d_in[1];
  float* out = (float*)d_out;
  float* wsf = (float*)d_ws;
  (void)in_sizes; (void)n_in; (void)out_size; (void)ws_size;

  sq_kernel    <<<dim3(NMIN / 4),  dim3(256), 0, stream>>>(X, wsf);
  smote_main   <<<dim3(512),       dim3(256), 0, stream>>>(X, wsf);
  rerank_kernel<<<dim3(NMIN),      dim3(256), 0, stream>>>(X, wsf);
  gen_kernel   <<<dim3(NMIN / 32), dim3(256), 0, stream>>>(X, wsf, out);
  copy_kernel  <<<dim3(2048),      dim3(256), 0, stream>>>(X, y, out);
}